// Round 1
// baseline (256.588 us; speedup 1.0000x reference)
//
#include <hip/hip_runtime.h>
#include <hip/hip_bf16.h>

#define DD 8
#define CC 512
#define NN 4096
#define SPLITK 4
#define KSP (NN / SPLITK) /* 1024 */

typedef __bf16 bf16x8 __attribute__((ext_vector_type(8)));
typedef float  f32x4  __attribute__((ext_vector_type(4)));

__device__ __forceinline__ ushort f2bf(float f) {
  unsigned u = __float_as_uint(f);
  u = (u + 0x7fffu + ((u >> 16) & 1u)) >> 16;   // RNE
  return (ushort)u;
}
__device__ __forceinline__ float bf2f(ushort h) {
  return __uint_as_float(((unsigned)h) << 16);
}

__device__ __forceinline__ void gl_lds16(const ushort* g, ushort* l) {
  __builtin_amdgcn_global_load_lds(
      (const __attribute__((address_space(1))) void*)g,
      (__attribute__((address_space(3))) void*)l, 16, 0, 0);
}

// ---------------------------------------------------------------------------
// K0: x fp32 -> q_hi, q_lo (bf16, [d][c][n]) and qT_hi (bf16, [d][n][c])
// ---------------------------------------------------------------------------
__global__ __launch_bounds__(256) void k0_convert(
    const float* __restrict__ x, ushort* __restrict__ qh,
    ushort* __restrict__ ql, ushort* __restrict__ qt) {
  int d = blockIdx.z, ct = blockIdx.y, nt = blockIdx.x;
  __shared__ ushort T[64][68];
  int t = threadIdx.x;
  int rr = t >> 4;           // 0..15
  int c4 = (t & 15) * 4;     // 0..60
  const float* xb = x + ((size_t)(d * CC + ct * 64)) * NN + nt * 64;
#pragma unroll
  for (int it = 0; it < 4; ++it) {
    int r = it * 16 + rr;
    float4 v = *(const float4*)(xb + (size_t)r * NN + c4);
    ushort h0 = f2bf(v.x), h1 = f2bf(v.y), h2 = f2bf(v.z), h3 = f2bf(v.w);
    ushort l0 = f2bf(v.x - bf2f(h0)), l1 = f2bf(v.y - bf2f(h1));
    ushort l2 = f2bf(v.z - bf2f(h2)), l3 = f2bf(v.w - bf2f(h3));
    size_t qi = ((size_t)(d * CC + ct * 64 + r)) * NN + nt * 64 + c4;
    *(ushort4*)(qh + qi) = make_ushort4(h0, h1, h2, h3);
    *(ushort4*)(ql + qi) = make_ushort4(l0, l1, l2, l3);
    *(ushort4*)&T[r][c4] = make_ushort4(h0, h1, h2, h3);
  }
  __syncthreads();
#pragma unroll
  for (int it = 0; it < 4; ++it) {
    int nl = it * 16 + rr;
    ushort4 v = make_ushort4(T[c4 + 0][nl], T[c4 + 1][nl], T[c4 + 2][nl], T[c4 + 3][nl]);
    *(ushort4*)(qt + ((size_t)(d * NN + nt * 64 + nl)) * CC + ct * 64 + c4) = v;
  }
}

// ---------------------------------------------------------------------------
// K1: E_partial[s][d][i][j] = sum_{k in split s} Q_i . Q_j  (bf16x3 split)
//     BM=BN=128, BK=32, 4 waves (2x2, 64x64 each), split-K = 4
// ---------------------------------------------------------------------------
__global__ __launch_bounds__(256, 2) void k1_gram(
    const ushort* __restrict__ qh, const ushort* __restrict__ ql,
    float* __restrict__ Ep) {
  __shared__ ushort As[2][128 * 32];   // [hi/lo][m][k]
  __shared__ ushort Bs[2][128 * 32];
  int b = blockIdx.x;
  int s = b & 3, tmn = (b >> 2) & 15, d = b >> 6;
  int tm = tmn >> 2, tn = tmn & 3;
  int t = threadIdx.x, lane = t & 63, w = t >> 6;
  int wm = (w >> 1) * 64, wn = (w & 1) * 64;
  int qd = lane >> 4, fr = lane & 15;

  // wave w stages: 0->As_hi 1->As_lo 2->Bs_hi 3->Bs_lo
  const ushort* srcbase = (w & 1) ? ql : qh;
  int rowblk = (w < 2) ? tm : tn;
  const ushort* gsrc = srcbase +
      ((size_t)(d * CC + rowblk * 128 + (lane >> 2))) * NN +
      (size_t)s * KSP + (lane & 3) * 8;
  ushort* ldst = (w < 2) ? As[w & 1] : Bs[w & 1];

  f32x4 acc[4][4];
#pragma unroll
  for (int i = 0; i < 4; ++i)
#pragma unroll
    for (int j = 0; j < 4; ++j) acc[i][j] = (f32x4){0.f, 0.f, 0.f, 0.f};

  for (int kk = 0; kk < KSP / 32; ++kk) {
    __syncthreads();
    const ushort* g0 = gsrc + (size_t)kk * 32;
#pragma unroll
    for (int c = 0; c < 8; ++c)
      gl_lds16(g0 + (size_t)c * 16 * NN, ldst + c * 512);
    __syncthreads();

    bf16x8 ah[4], al[4];
#pragma unroll
    for (int mi = 0; mi < 4; ++mi) {
      int off = (wm + mi * 16 + fr) * 32 + qd * 8;
      ah[mi] = *(const bf16x8*)&As[0][off];
      al[mi] = *(const bf16x8*)&As[1][off];
    }
#pragma unroll
    for (int ni = 0; ni < 4; ++ni) {
      int off = (wn + ni * 16 + fr) * 32 + qd * 8;
      bf16x8 bh = *(const bf16x8*)&Bs[0][off];
      bf16x8 bl = *(const bf16x8*)&Bs[1][off];
#pragma unroll
      for (int mi = 0; mi < 4; ++mi) {
        acc[mi][ni] = __builtin_amdgcn_mfma_f32_16x16x32_bf16(ah[mi], bh, acc[mi][ni], 0, 0, 0);
        acc[mi][ni] = __builtin_amdgcn_mfma_f32_16x16x32_bf16(ah[mi], bl, acc[mi][ni], 0, 0, 0);
        acc[mi][ni] = __builtin_amdgcn_mfma_f32_16x16x32_bf16(al[mi], bh, acc[mi][ni], 0, 0, 0);
      }
    }
  }

  size_t ebase = ((size_t)(s * DD + d)) * ((size_t)CC * CC);
#pragma unroll
  for (int mi = 0; mi < 4; ++mi) {
    int r0 = tm * 128 + wm + mi * 16 + qd * 4;
#pragma unroll
    for (int ni = 0; ni < 4; ++ni) {
      int c0 = tn * 128 + wn + ni * 16 + fr;
      float* ep = Ep + ebase + (size_t)r0 * CC + c0;
#pragma unroll
      for (int r = 0; r < 4; ++r) ep[(size_t)r * CC] = acc[mi][ni][r];
    }
  }
}

// ---------------------------------------------------------------------------
// K2: reduce split-K partials + softmax(-E) + softmax(att1+atten),
//     write att2^T as bf16 ([d][j][i]) via LDS transpose.
// ---------------------------------------------------------------------------
__device__ __forceinline__ float bred(float v, float* red, int op) {
#pragma unroll
  for (int o = 32; o > 0; o >>= 1) {
    float other = __shfl_xor(v, o, 64);
    v = (op == 0) ? fminf(v, other) : (op == 1) ? (v + other) : fmaxf(v, other);
  }
  __syncthreads();
  if ((threadIdx.x & 63) == 0) red[threadIdx.x >> 6] = v;
  __syncthreads();
  if (op == 0) return fminf(fminf(red[0], red[1]), fminf(red[2], red[3]));
  if (op == 1) return red[0] + red[1] + red[2] + red[3];
  return fmaxf(fmaxf(red[0], red[1]), fmaxf(red[2], red[3]));
}

__global__ __launch_bounds__(256) void k2_softmax(
    const float* __restrict__ Ep, const float* __restrict__ atten,
    ushort* __restrict__ a2t) {
  int d = blockIdx.y, i0 = blockIdx.x * 16;
  int t = threadIdx.x;
  __shared__ float red[4];
  __shared__ ushort T[512][17];
  const size_t SP = (size_t)DD * CC * CC;
  for (int r = 0; r < 16; ++r) {
    size_t base = ((size_t)(d * CC + i0 + r)) * CC;
    float e0 = Ep[base + t] + Ep[SP + base + t] + Ep[2 * SP + base + t] + Ep[3 * SP + base + t];
    float e1 = Ep[base + t + 256] + Ep[SP + base + t + 256] +
               Ep[2 * SP + base + t + 256] + Ep[3 * SP + base + t + 256];
    float mn = bred(fminf(e0, e1), red, 0);
    // softmax(rowmax - E) == softmax(-E); shift by -Emin for stability
    float p0 = __expf(mn - e0), p1 = __expf(mn - e1);
    float s1 = bred(p0 + p1, red, 1);
    float inv1 = 1.0f / s1;
    float t0 = p0 * inv1 + atten[base + t];
    float t1 = p1 * inv1 + atten[base + t + 256];
    float mx = bred(fmaxf(t0, t1), red, 2);
    float q0 = __expf(t0 - mx), q1 = __expf(t1 - mx);
    float s2 = bred(q0 + q1, red, 1);
    float inv2 = 1.0f / s2;
    T[t][r] = f2bf(q0 * inv2);
    T[t + 256][r] = f2bf(q1 * inv2);
  }
  __syncthreads();
#pragma unroll
  for (int jj = 0; jj < 2; ++jj) {
    int j = t + jj * 256;
    size_t ob = ((size_t)(d * CC + j)) * CC + i0;
#pragma unroll
    for (int c4 = 0; c4 < 4; ++c4) {
      ushort4 v = make_ushort4(T[j][c4 * 4], T[j][c4 * 4 + 1],
                               T[j][c4 * 4 + 2], T[j][c4 * 4 + 3]);
      *(ushort4*)(a2t + ob + c4 * 4) = v;
    }
  }
}

// ---------------------------------------------------------------------------
// K3: out[d][j][n] = gamma * sum_i att2T[d][j][i] * qT[d][n][i] + x[d][j][n]
//     BM=128 (j), BN=128 (n), K=512, NT GEMM
// ---------------------------------------------------------------------------
__global__ __launch_bounds__(256, 2) void k3_out(
    const ushort* __restrict__ a2t, const ushort* __restrict__ qt,
    const float* __restrict__ x, const float* __restrict__ gamma,
    float* __restrict__ out) {
  __shared__ ushort As[128 * 32];
  __shared__ ushort Bs[128 * 32];
  int b = blockIdx.x;
  int nt = b & 31, jt = (b >> 5) & 3, d = b >> 7;
  int t = threadIdx.x, lane = t & 63, w = t >> 6;
  int wm = (w >> 1) * 64, wn = (w & 1) * 64;
  int qd = lane >> 4, fr = lane & 15;

  const ushort* src = (w < 2)
      ? (a2t + (size_t)d * CC * CC + (size_t)(jt * 128) * CC)
      : (qt + (size_t)d * NN * CC + (size_t)(nt * 128) * CC);
  ushort* ldst = (w < 2) ? As : Bs;
  int cbase = (w & 1) * 4;
  const ushort* g0 = src + ((size_t)(cbase * 16 + (lane >> 2))) * CC + (lane & 3) * 8;
  ushort* l0 = ldst + cbase * 16 * 32;

  f32x4 acc[4][4];
#pragma unroll
  for (int i = 0; i < 4; ++i)
#pragma unroll
    for (int j = 0; j < 4; ++j) acc[i][j] = (f32x4){0.f, 0.f, 0.f, 0.f};

  for (int kk = 0; kk < CC / 32; ++kk) {
    __syncthreads();
#pragma unroll
    for (int c = 0; c < 4; ++c)
      gl_lds16(g0 + kk * 32 + (size_t)(c * 16) * CC, l0 + c * 512);
    __syncthreads();

    bf16x8 a[4];
#pragma unroll
    for (int mi = 0; mi < 4; ++mi)
      a[mi] = *(const bf16x8*)&As[(wm + mi * 16 + fr) * 32 + qd * 8];
#pragma unroll
    for (int ni = 0; ni < 4; ++ni) {
      bf16x8 bb = *(const bf16x8*)&Bs[(wn + ni * 16 + fr) * 32 + qd * 8];
#pragma unroll
      for (int mi = 0; mi < 4; ++mi)
        acc[mi][ni] = __builtin_amdgcn_mfma_f32_16x16x32_bf16(a[mi], bb, acc[mi][ni], 0, 0, 0);
    }
  }

  float g = gamma[0];
#pragma unroll
  for (int mi = 0; mi < 4; ++mi) {
    int j0 = jt * 128 + wm + mi * 16 + qd * 4;
#pragma unroll
    for (int ni = 0; ni < 4; ++ni) {
      int n0 = nt * 128 + wn + ni * 16 + fr;
#pragma unroll
      for (int r = 0; r < 4; ++r) {
        size_t idx = ((size_t)(d * CC + j0 + r)) * NN + n0;
        out[idx] = g * acc[mi][ni][r] + x[idx];
      }
    }
  }
}

// ---------------------------------------------------------------------------
extern "C" void kernel_launch(void* const* d_in, const int* in_sizes, int n_in,
                              void* d_out, int out_size, void* d_ws, size_t ws_size,
                              hipStream_t stream) {
  (void)in_sizes; (void)n_in; (void)out_size; (void)ws_size;
  const float* x     = (const float*)d_in[0];
  const float* atten = (const float*)d_in[1];
  const float* gamma = (const float*)d_in[2];
  float* out = (float*)d_out;

  char* ws = (char*)d_ws;
  ushort* qh  = (ushort*)(ws);                    // 33554432 B
  ushort* ql  = (ushort*)(ws + 33554432);         // 33554432 B
  ushort* qt  = (ushort*)(ws + 67108864);         // 33554432 B
  float*  Ep  = (float*) (ws + 100663296);        // 33554432 B (4 split-K partials)
  ushort* a2t = (ushort*)(ws + 134217728);        // 4194304 B
  // total ws use: 138412032 B

  k0_convert<<<dim3(64, 8, 8), 256, 0, stream>>>(x, qh, ql, qt);
  k1_gram   <<<dim3(512), 256, 0, stream>>>(qh, ql, Ep);
  k2_softmax<<<dim3(32, 8), 256, 0, stream>>>(Ep, atten, a2t);
  k3_out    <<<dim3(1024), 256, 0, stream>>>(a2t, qt, x, gamma, out);
}

// Round 2
// 234.965 us; speedup vs baseline: 1.0920x; 1.0920x over previous
//
#include <hip/hip_runtime.h>
#include <hip/hip_bf16.h>

#define DD 8
#define CC 512
#define NN 4096

typedef __bf16 bf16x8 __attribute__((ext_vector_type(8)));
typedef float  f32x4  __attribute__((ext_vector_type(4)));
typedef ushort ush8   __attribute__((ext_vector_type(8)));

__device__ __forceinline__ ushort f2bf(float f) {
  unsigned u = __float_as_uint(f);
  u = (u + 0x7fffu + ((u >> 16) & 1u)) >> 16;   // RNE
  return (ushort)u;
}
__device__ __forceinline__ float bf2f(ushort h) {
  return __uint_as_float(((unsigned)h) << 16);
}

__device__ __forceinline__ void gl_lds16(const ushort* g, ushort* l) {
  __builtin_amdgcn_global_load_lds(
      (const __attribute__((address_space(1))) void*)g,
      (__attribute__((address_space(3))) void*)l, 16, 0, 0);
}

// ---------------------------------------------------------------------------
// K0: x fp32 -> q_hi, q_lo (bf16, [d][c][n]) and qT_hi (bf16, [d][n][c])
// ---------------------------------------------------------------------------
__global__ __launch_bounds__(256) void k0_convert(
    const float* __restrict__ x, ushort* __restrict__ qh,
    ushort* __restrict__ ql, ushort* __restrict__ qt) {
  int d = blockIdx.z, ct = blockIdx.y, nt = blockIdx.x;
  __shared__ ushort T[64][68];
  int t = threadIdx.x;
  int rr = t >> 4;           // 0..15
  int c4 = (t & 15) * 4;     // 0..60
  const float* xb = x + ((size_t)(d * CC + ct * 64)) * NN + nt * 64;
#pragma unroll
  for (int it = 0; it < 4; ++it) {
    int r = it * 16 + rr;
    float4 v = *(const float4*)(xb + (size_t)r * NN + c4);
    ushort h0 = f2bf(v.x), h1 = f2bf(v.y), h2 = f2bf(v.z), h3 = f2bf(v.w);
    ushort l0 = f2bf(v.x - bf2f(h0)), l1 = f2bf(v.y - bf2f(h1));
    ushort l2 = f2bf(v.z - bf2f(h2)), l3 = f2bf(v.w - bf2f(h3));
    size_t qi = ((size_t)(d * CC + ct * 64 + r)) * NN + nt * 64 + c4;
    *(ushort4*)(qh + qi) = make_ushort4(h0, h1, h2, h3);
    *(ushort4*)(ql + qi) = make_ushort4(l0, l1, l2, l3);
    *(ushort4*)&T[r][c4] = make_ushort4(h0, h1, h2, h3);
  }
  __syncthreads();
#pragma unroll
  for (int it = 0; it < 4; ++it) {
    int nl = it * 16 + rr;
    ushort4 v = make_ushort4(T[c4 + 0][nl], T[c4 + 1][nl], T[c4 + 2][nl], T[c4 + 3][nl]);
    *(ushort4*)(qt + ((size_t)(d * NN + nt * 64 + nl)) * CC + ct * 64 + c4) = v;
  }
}

// ---------------------------------------------------------------------------
// K1: Gram partials, upper-triangle tiles only + symmetric mirror store.
//     Each split-K partial is symmetric, so tile (tm,tn) transposed = (tn,tm).
//     Mirror store is float4 (acc regs run along rows).
// ---------------------------------------------------------------------------
__global__ __launch_bounds__(256, 2) void k1_gram(
    const ushort* __restrict__ qh, const ushort* __restrict__ ql,
    float* __restrict__ Ep, int ns, int nkk, int ksp) {
  __shared__ ushort As[2][128 * 32];   // [hi/lo][m][k]
  __shared__ ushort Bs[2][128 * 32];
  int b = blockIdx.x;
  int s = b % ns;
  int rem = b / ns;
  int tile = rem % 10, d = rem / 10;
  // triangle tile lookup (nibble-packed): tm = row-tile, tn = col-tile, tm<=tn
  int tm = (int)((0x3221110000ULL >> (tile * 4)) & 15ULL);
  int tn = (int)((0x3323213210ULL >> (tile * 4)) & 15ULL);
  int t = threadIdx.x, lane = t & 63, w = t >> 6;
  int wm = (w >> 1) * 64, wn = (w & 1) * 64;
  int qd = lane >> 4, fr = lane & 15;

  // wave w stages: 0->As_hi 1->As_lo 2->Bs_hi 3->Bs_lo
  const ushort* srcbase = (w & 1) ? ql : qh;
  int rowblk = (w < 2) ? tm : tn;
  const ushort* gsrc = srcbase +
      ((size_t)(d * CC + rowblk * 128 + (lane >> 2))) * NN +
      (size_t)s * ksp + (lane & 3) * 8;
  ushort* ldst = (w < 2) ? As[w & 1] : Bs[w & 1];

  f32x4 acc[4][4];
#pragma unroll
  for (int i = 0; i < 4; ++i)
#pragma unroll
    for (int j = 0; j < 4; ++j) acc[i][j] = (f32x4){0.f, 0.f, 0.f, 0.f};

  for (int kk = 0; kk < nkk; ++kk) {
    __syncthreads();
    const ushort* g0 = gsrc + (size_t)kk * 32;
#pragma unroll
    for (int c = 0; c < 8; ++c)
      gl_lds16(g0 + (size_t)c * 16 * NN, ldst + c * 512);
    __syncthreads();

    bf16x8 ah[4], al[4];
#pragma unroll
    for (int mi = 0; mi < 4; ++mi) {
      int off = (wm + mi * 16 + fr) * 32 + qd * 8;
      ah[mi] = *(const bf16x8*)&As[0][off];
      al[mi] = *(const bf16x8*)&As[1][off];
    }
#pragma unroll
    for (int ni = 0; ni < 4; ++ni) {
      int off = (wn + ni * 16 + fr) * 32 + qd * 8;
      bf16x8 bh = *(const bf16x8*)&Bs[0][off];
      bf16x8 bl = *(const bf16x8*)&Bs[1][off];
#pragma unroll
      for (int mi = 0; mi < 4; ++mi) {
        acc[mi][ni] = __builtin_amdgcn_mfma_f32_16x16x32_bf16(ah[mi], bh, acc[mi][ni], 0, 0, 0);
        acc[mi][ni] = __builtin_amdgcn_mfma_f32_16x16x32_bf16(ah[mi], bl, acc[mi][ni], 0, 0, 0);
        acc[mi][ni] = __builtin_amdgcn_mfma_f32_16x16x32_bf16(al[mi], bh, acc[mi][ni], 0, 0, 0);
      }
    }
  }

  size_t ebase = ((size_t)(s * DD + d)) * ((size_t)CC * CC);
  // normal store (tile tm,tn): scalar strided
#pragma unroll
  for (int mi = 0; mi < 4; ++mi) {
    int r0 = tm * 128 + wm + mi * 16 + qd * 4;
#pragma unroll
    for (int ni = 0; ni < 4; ++ni) {
      int c0 = tn * 128 + wn + ni * 16 + fr;
      float* ep = Ep + ebase + (size_t)r0 * CC + c0;
#pragma unroll
      for (int r = 0; r < 4; ++r) ep[(size_t)r * CC] = acc[mi][ni][r];
    }
  }
  // mirror store (tile tn,tm) = transpose: per-lane float4 along rows
  if (tm != tn) {
#pragma unroll
    for (int mi = 0; mi < 4; ++mi) {
      int r0 = tm * 128 + wm + mi * 16 + qd * 4;
#pragma unroll
      for (int ni = 0; ni < 4; ++ni) {
        int c0 = tn * 128 + wn + ni * 16 + fr;
        float4 v = make_float4(acc[mi][ni][0], acc[mi][ni][1],
                               acc[mi][ni][2], acc[mi][ni][3]);
        *(float4*)(Ep + ebase + (size_t)c0 * CC + r0) = v;
      }
    }
  }
}

// ---------------------------------------------------------------------------
// K2: wave-per-row reduce + double softmax + transposed bf16 write via LDS
// ---------------------------------------------------------------------------
__device__ __forceinline__ float wmin(float v) {
#pragma unroll
  for (int o = 32; o > 0; o >>= 1) v = fminf(v, __shfl_xor(v, o));
  return v;
}
__device__ __forceinline__ float wmax(float v) {
#pragma unroll
  for (int o = 32; o > 0; o >>= 1) v = fmaxf(v, __shfl_xor(v, o));
  return v;
}
__device__ __forceinline__ float wsum(float v) {
#pragma unroll
  for (int o = 32; o > 0; o >>= 1) v += __shfl_xor(v, o);
  return v;
}

__global__ __launch_bounds__(256) void k2_softmax(
    const float* __restrict__ Ep, const float* __restrict__ atten,
    ushort* __restrict__ a2t, int ns) {
  int d = blockIdx.y, i0 = blockIdx.x * 8;
  int t = threadIdx.x, lane = t & 63, w = t >> 6;
  int j8 = lane * 8;
  __shared__ ushort T[8][520];
  const size_t SP = (size_t)DD * CC * CC;

#pragma unroll
  for (int r2 = 0; r2 < 2; ++r2) {
    int ri = w * 2 + r2;
    size_t base = ((size_t)(d * CC + i0 + ri)) * CC + j8;
    f32x4 a0 = (f32x4){0.f, 0.f, 0.f, 0.f};
    f32x4 a1 = (f32x4){0.f, 0.f, 0.f, 0.f};
    for (int s = 0; s < ns; ++s) {
      const float* p = Ep + (size_t)s * SP + base;
      a0 += *(const f32x4*)p;
      a1 += *(const f32x4*)(p + 4);
    }
    float mn = fminf(fminf(fminf(a0[0], a0[1]), fminf(a0[2], a0[3])),
                     fminf(fminf(a1[0], a1[1]), fminf(a1[2], a1[3])));
    mn = wmin(mn);
    float p0 = __expf(mn - a0[0]), p1 = __expf(mn - a0[1]);
    float p2 = __expf(mn - a0[2]), p3 = __expf(mn - a0[3]);
    float p4 = __expf(mn - a1[0]), p5 = __expf(mn - a1[1]);
    float p6 = __expf(mn - a1[2]), p7 = __expf(mn - a1[3]);
    float s1 = wsum(p0 + p1 + p2 + p3 + p4 + p5 + p6 + p7);
    float inv1 = 1.0f / s1;
    const float* ap = atten + base;
    f32x4 t0 = *(const f32x4*)ap;
    f32x4 t1 = *(const f32x4*)(ap + 4);
    float u0 = p0 * inv1 + t0[0], u1 = p1 * inv1 + t0[1];
    float u2 = p2 * inv1 + t0[2], u3 = p3 * inv1 + t0[3];
    float u4 = p4 * inv1 + t1[0], u5 = p5 * inv1 + t1[1];
    float u6 = p6 * inv1 + t1[2], u7 = p7 * inv1 + t1[3];
    float mx = wmax(fmaxf(fmaxf(fmaxf(u0, u1), fmaxf(u2, u3)),
                          fmaxf(fmaxf(u4, u5), fmaxf(u6, u7))));
    float q0 = __expf(u0 - mx), q1 = __expf(u1 - mx);
    float q2 = __expf(u2 - mx), q3 = __expf(u3 - mx);
    float q4 = __expf(u4 - mx), q5 = __expf(u5 - mx);
    float q6 = __expf(u6 - mx), q7 = __expf(u7 - mx);
    float s2 = wsum(q0 + q1 + q2 + q3 + q4 + q5 + q6 + q7);
    float inv2 = 1.0f / s2;
    ush8 o;
    o[0] = f2bf(q0 * inv2); o[1] = f2bf(q1 * inv2);
    o[2] = f2bf(q2 * inv2); o[3] = f2bf(q3 * inv2);
    o[4] = f2bf(q4 * inv2); o[5] = f2bf(q5 * inv2);
    o[6] = f2bf(q6 * inv2); o[7] = f2bf(q7 * inv2);
    *(ush8*)&T[ri][j8] = o;
  }
  __syncthreads();
  // write att2^T: a2t[d][j][i0..i0+7], coalesced 16B per thread
#pragma unroll
  for (int it = 0; it < 2; ++it) {
    int j = t + it * 256;
    ush8 o;
#pragma unroll
    for (int k = 0; k < 8; ++k) o[k] = T[k][j];
    *(ush8*)&a2t[((size_t)(d * CC + j)) * CC + i0] = o;
  }
}

// ---------------------------------------------------------------------------
// K3: out[d][j][n] = gamma * sum_i att2T[d][j][i] * qT[d][n][i] + x[d][j][n]
//     Operands swapped (D rows = n) so epilogue is per-lane float4 along n.
// ---------------------------------------------------------------------------
__global__ __launch_bounds__(256, 2) void k3_out(
    const ushort* __restrict__ a2t, const ushort* __restrict__ qt,
    const float* __restrict__ x, const float* __restrict__ gamma,
    float* __restrict__ out) {
  __shared__ ushort As[128 * 32];   // a2t tile: 128 j-rows x 32 k
  __shared__ ushort Bs[128 * 32];   // qt tile: 128 n-rows x 32 k
  int b = blockIdx.x;
  int nt = b & 31, jt = (b >> 5) & 3, d = b >> 7;
  int t = threadIdx.x, lane = t & 63, w = t >> 6;
  int wj = (w >> 1) * 64, wn2 = (w & 1) * 64;
  int qd = lane >> 4, fr = lane & 15;

  const ushort* src = (w < 2)
      ? (a2t + (size_t)d * CC * CC + (size_t)(jt * 128) * CC)
      : (qt + (size_t)d * NN * CC + (size_t)(nt * 128) * CC);
  ushort* ldst = (w < 2) ? As : Bs;
  int cbase = (w & 1) * 4;
  const ushort* g0 = src + ((size_t)(cbase * 16 + (lane >> 2))) * CC + (lane & 3) * 8;
  ushort* l0 = ldst + cbase * 16 * 32;

  f32x4 acc[4][4];   // acc[ii(n)][jj(j)]
#pragma unroll
  for (int i = 0; i < 4; ++i)
#pragma unroll
    for (int j = 0; j < 4; ++j) acc[i][j] = (f32x4){0.f, 0.f, 0.f, 0.f};

  for (int kk = 0; kk < CC / 32; ++kk) {
    __syncthreads();
#pragma unroll
    for (int c = 0; c < 4; ++c)
      gl_lds16(g0 + kk * 32 + (size_t)(c * 16) * CC, l0 + c * 512);
    __syncthreads();

    bf16x8 qf[4];
#pragma unroll
    for (int ii = 0; ii < 4; ++ii)
      qf[ii] = *(const bf16x8*)&Bs[(wn2 + ii * 16 + fr) * 32 + qd * 8];
#pragma unroll
    for (int jj = 0; jj < 4; ++jj) {
      bf16x8 af = *(const bf16x8*)&As[(wj + jj * 16 + fr) * 32 + qd * 8];
#pragma unroll
      for (int ii = 0; ii < 4; ++ii)
        acc[ii][jj] = __builtin_amdgcn_mfma_f32_16x16x32_bf16(qf[ii], af, acc[ii][jj], 0, 0, 0);
    }
  }

  float g = gamma[0];
#pragma unroll
  for (int ii = 0; ii < 4; ++ii) {
    int n0 = nt * 128 + wn2 + ii * 16 + qd * 4;
#pragma unroll
    for (int jj = 0; jj < 4; ++jj) {
      int j = jt * 128 + wj + jj * 16 + fr;
      size_t idx = ((size_t)(d * CC + j)) * NN + n0;
      float4 xv = *(const float4*)(x + idx);
      float4 ov = make_float4(g * acc[ii][jj][0] + xv.x,
                              g * acc[ii][jj][1] + xv.y,
                              g * acc[ii][jj][2] + xv.z,
                              g * acc[ii][jj][3] + xv.w);
      *(float4*)(out + idx) = ov;
    }
  }
}

// ---------------------------------------------------------------------------
extern "C" void kernel_launch(void* const* d_in, const int* in_sizes, int n_in,
                              void* d_out, int out_size, void* d_ws, size_t ws_size,
                              hipStream_t stream) {
  (void)in_sizes; (void)n_in; (void)out_size;
  const float* x     = (const float*)d_in[0];
  const float* atten = (const float*)d_in[1];
  const float* gamma = (const float*)d_in[2];
  float* out = (float*)d_out;

  char* ws = (char*)d_ws;
  ushort* qh  = (ushort*)(ws);                    // 33554432 B
  ushort* ql  = (ushort*)(ws + 33554432);         // 33554432 B
  ushort* qt  = (ushort*)(ws + 67108864);         // 33554432 B
  ushort* a2t = (ushort*)(ws + 100663296);        // 4194304 B
  float*  Ep  = (float*) (ws + 104857600);        // ns * 8388608 B

  // split-K: 8 if workspace allows (Ep = 67.1 MB), else 4 (proven footprint)
  int ns = (ws_size >= 104857600ULL + 8ULL * 8388608ULL) ? 8 : 4;
  int ksp = NN / ns;
  int nkk = ksp / 32;

  k0_convert<<<dim3(64, 8, 8), 256, 0, stream>>>(x, qh, ql, qt);
  k1_gram   <<<dim3(80 * ns), 256, 0, stream>>>(qh, ql, Ep, ns, nkk, ksp);
  k2_softmax<<<dim3(64, 8), 256, 0, stream>>>(Ep, atten, a2t, ns);
  k3_out    <<<dim3(1024), 256, 0, stream>>>(a2t, qt, x, gamma, out);
}